// Round 13
// baseline (221.059 us; speedup 1.0000x reference)
//
#include <hip/hip_runtime.h>
#include <hip/hip_bf16.h>
#include <stdint.h>

// Problem constants (from reference)
#define N_ROWS   32768      // BSZ*TSZ
#define M_CODES  1024
#define D_DIM    256
#define BN       32         // rows per block
#define NBLOCKS  (N_ROWS / BN)   // 1024
#define EPS      1.0f       // argmin refinement window (~50 sigma of bf16 dist error)
#define CAND_MAX 16

// Output layout (flat f32, concat in reference return order)
#define OFF_Q      0
#define OFF_CODEP  8388608
#define OFF_PROBP  8388609
#define OFF_INDS   8388610
#define OFF_COMMIT 8421378

typedef __attribute__((ext_vector_type(8))) short bf16x8;
typedef __attribute__((ext_vector_type(8))) unsigned short u16x8;
typedef __attribute__((ext_vector_type(4))) float f32x4;

__device__ __forceinline__ unsigned short f2bf(float f) {
    __hip_bfloat16 h = __float2bfloat16(f);      // HW cvt (RNE); m240: scalar cast compiles well
    return __builtin_bit_cast(unsigned short, h);
}

// ---------------------------------------------------------------------------
// Prep: emb f32 -> bf16 in MFMA-fragment order + ||e||^2 + zero accumulators.
// efrag element off = ((c16*8 + ks)*64 + lane)*8, lane = (kgrp<<4)|(c&15)
// grid 1024 blocks (one code) x 64 threads
__global__ __launch_bounds__(64) void vq_prep(
    const float* __restrict__ emb,
    unsigned short* __restrict__ efrag, float* __restrict__ enorm,
    float* __restrict__ pprobs_g, unsigned int* __restrict__ counts_g,
    float* __restrict__ commit_g)
{
    const int r = blockIdx.x, t = threadIdx.x;

    if (t < 32) {
        const float4 a = *(const float4*)(emb + r * D_DIM + t * 8);
        const float4 b = *(const float4*)(emb + r * D_DIM + t * 8 + 4);
        u16x8 H;
        H[0] = f2bf(a.x); H[1] = f2bf(a.y); H[2] = f2bf(a.z); H[3] = f2bf(a.w);
        H[4] = f2bf(b.x); H[5] = f2bf(b.y); H[6] = f2bf(b.z); H[7] = f2bf(b.w);
        const int off = (((r >> 4) * 8 + (t >> 2)) * 64 + (((t & 3) << 4) | (r & 15))) * 8;
        *(u16x8*)(efrag + off) = H;
    }

    const float4 v = *(const float4*)(emb + r * D_DIM + t * 4);
    float n = v.x * v.x + v.y * v.y + v.z * v.z + v.w * v.w;
    #pragma unroll
    for (int off = 32; off; off >>= 1) n += __shfl_xor(n, off);
    if (t == 0) {
        enorm[r] = n;
        pprobs_g[r] = 0.0f;
        counts_g[r] = 0u;
        if (r == 0) commit_g[0] = 0.0f;
    }
}

// ---------------------------------------------------------------------------
// Main: block = 32 rows x 1024 codes, 8 waves; wave = 32 rows x cols [w*128,+128).
// A-fragments in registers (no LDS staging). B double-buffered from L2-resident
// efrag, first buffer issued BEFORE the A-build so its latency hides under the
// cvt VALU work. Epilogue register-resident; exact-f32 refinement for argmin.
__global__ __launch_bounds__(512, 2) void vq_main(
    const float* __restrict__ xg, const float* __restrict__ embf,
    const unsigned short* __restrict__ efrag, const float* __restrict__ enorm,
    float* __restrict__ pprobs_g, unsigned int* __restrict__ counts_g,
    float* __restrict__ commit_g,
    float* __restrict__ out_q, float* __restrict__ out_inds)
{
    __shared__ float wmin[8][32];
    __shared__ float wsum[8][32];
    __shared__ float rmin[32];
    __shared__ float rinv[32];
    __shared__ int   cand[32][CAND_MAX];
    __shared__ int   ccnt[32];

    const int tid  = threadIdx.x;
    const int wave = tid >> 6, lane = tid & 63;
    const int lrow = lane & 15, lg = lane >> 4;
    const int row0 = blockIdx.x * BN;
    const int wc0  = wave * 128;         // wave's first col

    if (tid < 32) ccnt[tid] = 0;

    // ---- issue first B buffer (cf=0) EARLY: latency hides under A-build VALU
    const char* bb = (const char*)efrag + wave * 65536 + lane * 16;
    bf16x8 bA[8], bB[8];
    #pragma unroll
    for (int ks = 0; ks < 8; ++ks)
        bA[ks] = *(const bf16x8*)(bb + ks * 1024);

    // ---- A-fragments: x[row0 + rf*16 + lrow][ks*32 + lg*8 .. +8] -> regs (bf16)
    bf16x8 a[2][8];
    #pragma unroll
    for (int rf = 0; rf < 2; ++rf) {
        const float* xr = xg + (size_t)(row0 + rf * 16 + lrow) * D_DIM + lg * 8;
        #pragma unroll
        for (int ks = 0; ks < 8; ++ks) {
            const float4 v0 = *(const float4*)(xr + ks * 32);
            const float4 v1 = *(const float4*)(xr + ks * 32 + 4);
            u16x8 H;
            H[0] = f2bf(v0.x); H[1] = f2bf(v0.y); H[2] = f2bf(v0.z); H[3] = f2bf(v0.w);
            H[4] = f2bf(v1.x); H[5] = f2bf(v1.y); H[6] = f2bf(v1.z); H[7] = f2bf(v1.w);
            a[rf][ks] = __builtin_bit_cast(bf16x8, H);
        }
    }

    // ---- GEMM: acc[rf][cf][j], row_local = rf*16 + lg*4 + j, col = wc0 + cf*16 + lrow
    f32x4 acc[2][8];
    #pragma unroll
    for (int rf = 0; rf < 2; ++rf)
        #pragma unroll
        for (int cf = 0; cf < 8; ++cf)
            acc[rf][cf] = (f32x4){0.f, 0.f, 0.f, 0.f};

    #pragma unroll
    for (int cfp = 0; cfp < 4; ++cfp) {
        const int cfe = 2 * cfp, cfo = 2 * cfp + 1;
        // prefetch odd buffer
        #pragma unroll
        for (int ks = 0; ks < 8; ++ks)
            bB[ks] = *(const bf16x8*)(bb + cfo * 8192 + ks * 1024);
        // MFMA even (uses bA)
        #pragma unroll
        for (int ks = 0; ks < 8; ++ks) {
            acc[0][cfe] = __builtin_amdgcn_mfma_f32_16x16x32_bf16(a[0][ks], bA[ks], acc[0][cfe], 0, 0, 0);
            acc[1][cfe] = __builtin_amdgcn_mfma_f32_16x16x32_bf16(a[1][ks], bA[ks], acc[1][cfe], 0, 0, 0);
        }
        // prefetch next even buffer
        if (cfp < 3) {
            #pragma unroll
            for (int ks = 0; ks < 8; ++ks)
                bA[ks] = *(const bf16x8*)(bb + (cfe + 2) * 8192 + ks * 1024);
        }
        // MFMA odd (uses bB)
        #pragma unroll
        for (int ks = 0; ks < 8; ++ks) {
            acc[0][cfo] = __builtin_amdgcn_mfma_f32_16x16x32_bf16(a[0][ks], bB[ks], acc[0][cfo], 0, 0, 0);
            acc[1][cfo] = __builtin_amdgcn_mfma_f32_16x16x32_bf16(a[1][ks], bB[ks], acc[1][cfo], 0, 0, 0);
        }
    }

    // t = ||e||^2 - 2*dot
    #pragma unroll
    for (int cf = 0; cf < 8; ++cf) {
        const float en = enorm[wc0 + cf * 16 + lrow];
        #pragma unroll
        for (int rf = 0; rf < 2; ++rf)
            #pragma unroll
            for (int j = 0; j < 4; ++j)
                acc[rf][cf][j] = en - 2.0f * acc[rf][cf][j];
    }

    // ---- E1: per-wave per-row min over this wave's 128 cols
    #pragma unroll
    for (int rf = 0; rf < 2; ++rf) {
        #pragma unroll
        for (int j = 0; j < 4; ++j) {
            const int row = rf * 16 + lg * 4 + j;
            float m = acc[rf][0][j];
            #pragma unroll
            for (int cf = 1; cf < 8; ++cf) m = fminf(m, acc[rf][cf][j]);
            m = fminf(m, __shfl_xor(m, 1));
            m = fminf(m, __shfl_xor(m, 2));
            m = fminf(m, __shfl_xor(m, 4));
            m = fminf(m, __shfl_xor(m, 8));
            if (lrow == 0) wmin[wave][row] = m;
        }
    }
    __syncthreads();

    // ---- R1: cross-wave min -> rmin. wave w reduces rows w*4..w*4+3.
    {
        const int row = wave * 4 + lg;
        float m = wmin[lrow & 7][row];
        m = fminf(m, __shfl_xor(m, 1));
        m = fminf(m, __shfl_xor(m, 2));
        m = fminf(m, __shfl_xor(m, 4));
        if (lrow == 0) rmin[row] = m;
    }
    __syncthreads();

    // ---- E2: candidate scan + per-wave expsum partials (global min reference)
    #pragma unroll
    for (int rf = 0; rf < 2; ++rf) {
        #pragma unroll
        for (int j = 0; j < 4; ++j) {
            const int row = rf * 16 + lg * 4 + j;
            const float m = rmin[row];
            float s = 0.f;
            #pragma unroll
            for (int cf = 0; cf < 8; ++cf) {
                const float d = acc[rf][cf][j];
                if (d <= m + EPS) {
                    const int pos = atomicAdd(&ccnt[row], 1);
                    if (pos < CAND_MAX) cand[row][pos] = wc0 + cf * 16 + lrow;
                }
                s += __expf(m - d);
            }
            s += __shfl_xor(s, 1); s += __shfl_xor(s, 2);
            s += __shfl_xor(s, 4); s += __shfl_xor(s, 8);
            if (lrow == 0) wsum[wave][row] = s;
        }
    }
    __syncthreads();

    // ---- R2: expsum combine -> rinv; exact-f32 refinement fused with
    //          gather + out_q store + commitment. wave w owns rows w*4..w*4+3.
    float cacc = 0.f;
    {
        const int row = wave * 4 + lg;
        float s = wsum[lrow & 7][row];
        s += __shfl_xor(s, 1); s += __shfl_xor(s, 2); s += __shfl_xor(s, 4);
        if (lrow == 0) rinv[row] = 1.0f / s;

        for (int q = 0; q < 4; ++q) {
            const int r  = wave * 4 + q;
            const int rg = row0 + r;
            const int n  = min(ccnt[r], CAND_MAX);
            const float4 x4 = *(const float4*)(xg + (size_t)rg * D_DIM + lane * 4);
            float best = 3.4e38f; int bcol = 0x7fffffff;
            float4 be4 = (float4){0.f, 0.f, 0.f, 0.f};
            for (int i = 0; i < n; ++i) {
                const int c = cand[r][i];
                const float4 e4 = *(const float4*)(embf + (size_t)c * D_DIM + lane * 4);
                float dt = x4.x * e4.x + x4.y * e4.y + x4.z * e4.z + x4.w * e4.w;
                dt += __shfl_xor(dt, 1);  dt += __shfl_xor(dt, 2);
                dt += __shfl_xor(dt, 4);  dt += __shfl_xor(dt, 8);
                dt += __shfl_xor(dt, 16); dt += __shfl_xor(dt, 32);
                const float t = enorm[c] - 2.0f * dt;   // ||x||^2 cancels within row
                if (t < best || (t == best && c < bcol)) { best = t; bcol = c; be4 = e4; }
            }
            // winner is wave-uniform; be4 is this lane's slice of the winning row
            *(float4*)(out_q + (size_t)rg * D_DIM + lane * 4) = be4;
            const float dx = x4.x - be4.x, dy = x4.y - be4.y;
            const float dz = x4.z - be4.z, dw = x4.w - be4.w;
            cacc += dx * dx + dy * dy + dz * dz + dw * dw;
            if (lane == 0) {
                out_inds[rg] = (float)bcol;
                atomicAdd(&counts_g[bcol], 1u);
            }
        }
    }
    __syncthreads();

    // ---- E4: avg-softmax per-col accumulation (register-fed second exp pass)
    float rm[2][4], ri[2][4];
    #pragma unroll
    for (int rf = 0; rf < 2; ++rf)
        #pragma unroll
        for (int j = 0; j < 4; ++j) {
            const int row = rf * 16 + lg * 4 + j;
            rm[rf][j] = rmin[row];
            ri[rf][j] = rinv[row];
        }
    #pragma unroll
    for (int cf = 0; cf < 8; ++cf) {
        float t = 0.f;
        #pragma unroll
        for (int rf = 0; rf < 2; ++rf)
            #pragma unroll
            for (int j = 0; j < 4; ++j)
                t += __expf(rm[rf][j] - acc[rf][cf][j]) * ri[rf][j];
        t += __shfl_xor(t, 16);
        t += __shfl_xor(t, 32);
        if (lg == 0) unsafeAtomicAdd(&pprobs_g[wc0 + cf * 16 + lrow], t);
    }

    // ---- commitment partial
    cacc += __shfl_xor(cacc, 1);  cacc += __shfl_xor(cacc, 2);
    cacc += __shfl_xor(cacc, 4);  cacc += __shfl_xor(cacc, 8);
    cacc += __shfl_xor(cacc, 16); cacc += __shfl_xor(cacc, 32);
    if (lane == 0) unsafeAtomicAdd(commit_g, cacc);
}

// ---------------------------------------------------------------------------
// Final: the three scalars. 1 block x 1024 threads.
__global__ __launch_bounds__(1024) void vq_final(
    const float* __restrict__ pprobs_g, const unsigned int* __restrict__ counts_g,
    const float* __restrict__ commit_g, float* __restrict__ out)
{
    __shared__ float red1[16], red2[16];
    const int tid = threadIdx.x, wave = tid >> 6, lane = tid & 63;

    const float p_hard = (float)counts_g[tid] * (1.0f / (float)N_ROWS);
    float t1 = p_hard * log2f(p_hard + 1e-10f);
    const float p_avg = pprobs_g[tid] * (1.0f / (float)N_ROWS);
    float t2 = p_avg * log2f(p_avg + 1e-10f);

    #pragma unroll
    for (int off = 32; off; off >>= 1) { t1 += __shfl_xor(t1, off); t2 += __shfl_xor(t2, off); }
    if (lane == 0) { red1[wave] = t1; red2[wave] = t2; }
    __syncthreads();
    if (tid == 0) {
        float s1 = 0.0f, s2 = 0.0f;
        #pragma unroll
        for (int i = 0; i < 16; ++i) { s1 += red1[i]; s2 += red2[i]; }
        out[OFF_CODEP]  = -s1;
        out[OFF_PROBP]  = -s2;
        out[OFF_COMMIT] = commit_g[0] * (1.0f / (float)(N_ROWS * D_DIM));
    }
}

// ---------------------------------------------------------------------------
extern "C" void kernel_launch(void* const* d_in, const int* in_sizes, int n_in,
                              void* d_out, int out_size, void* d_ws, size_t ws_size,
                              hipStream_t stream)
{
    (void)in_sizes; (void)n_in; (void)out_size; (void)ws_size;
    const float* xg   = (const float*)d_in[0];
    const float* embf = (const float*)d_in[1];
    float* out = (float*)d_out;

    // ws layout (~537 KB): efrag | enorm | pprobs_g | counts_g | commit_g
    char* ws = (char*)d_ws;
    unsigned short* efrag    = (unsigned short*)(ws);
    float*          enorm    = (float*)(ws + 524288);
    float*          pprobs_g = (float*)(ws + 528384);
    unsigned int*   counts_g = (unsigned int*)(ws + 532480);
    float*          commit_g = (float*)(ws + 536576);

    hipLaunchKernelGGL(vq_prep, dim3(M_CODES), dim3(64), 0, stream,
                       embf, efrag, enorm, pprobs_g, counts_g, commit_g);

    hipLaunchKernelGGL(vq_main, dim3(NBLOCKS), dim3(512), 0, stream,
                       xg, embf, efrag, enorm, pprobs_g, counts_g, commit_g,
                       out + OFF_Q, out + OFF_INDS);

    hipLaunchKernelGGL(vq_final, dim3(1), dim3(1024), 0, stream,
                       pprobs_g, counts_g, commit_g, out);
}